// Round 1
// baseline (1535.824 us; speedup 1.0000x reference)
//
#include <hip/hip_runtime.h>
#include <cmath>

#define S_   4
#define DIN  1024
#define D_   256
#define B_   4
#define T_   4096
#define BT_  (B_*T_)
#define CHUNKS 128
#define CL   (T_/CHUNKS)   // 32

struct SC { float are[S_]; float aim[S_]; float bsc[S_]; };

// ---------------------------------------------------------------------------
// Kernel 1: triple GEMM over K=1024.
//   g1_raw  = x @ Wg1   (relu + bias applied)          -> ws g1  [s][bt][d]
//   dre     = x @ Wdr + bdr                            -> out[bt][s][0][d]
//   dim     = x @ Wdi + bdi                            -> out[bt][s][1][d]
// Tile: 64 rows (bt) x 64 cols (d), 256 threads, 4x4 per thread per matrix.
// ---------------------------------------------------------------------------
__global__ __launch_bounds__(256) void k1_gemm3(
    const float* __restrict__ x,
    const float* __restrict__ Wg1, const float* __restrict__ bg1,
    const float* __restrict__ Wdr, const float* __restrict__ bdr,
    const float* __restrict__ Wdi, const float* __restrict__ bdi,
    float* __restrict__ g1, float* __restrict__ out)
{
    const int s        = blockIdx.z;
    const int row_base = blockIdx.x * 64;
    const int col_base = blockIdx.y * 64;
    const int tid = threadIdx.x;
    const int tx = tid & 15, ty = tid >> 4;

    __shared__ float xs[16][68];          // [k][row], +4 pad keeps 16B align
    __shared__ float w1s[16][64];
    __shared__ float wrs[16][64];
    __shared__ float wis[16][64];

    float acc1[4][4] = {}, accr[4][4] = {}, acci[4][4] = {};

    const size_t wbase = (size_t)s * DIN * D_;

    for (int k0 = 0; k0 < DIN; k0 += 16) {
        // stage x tile: 64 rows x 16 k
        {
            const int kk = tid & 15, r = tid >> 4;
            #pragma unroll
            for (int p = 0; p < 4; ++p)
                xs[kk][r + p*16] = x[(size_t)(row_base + r + p*16) * DIN + k0 + kk];
        }
        // stage weight tiles: 16 k x 64 d (d contiguous -> coalesced)
        {
            const int dd = tid & 63, kk0 = tid >> 6;
            #pragma unroll
            for (int p = 0; p < 4; ++p) {
                const int kk = kk0 + p*4;
                const size_t idx = wbase + (size_t)(k0 + kk) * D_ + col_base + dd;
                w1s[kk][dd] = Wg1[idx];
                wrs[kk][dd] = Wdr[idx];
                wis[kk][dd] = Wdi[idx];
            }
        }
        __syncthreads();
        #pragma unroll
        for (int kk = 0; kk < 16; ++kk) {
            const float4 av = *(const float4*)&xs[kk][ty*4];
            const float4 b1 = *(const float4*)&w1s[kk][tx*4];
            const float4 br = *(const float4*)&wrs[kk][tx*4];
            const float4 bi = *(const float4*)&wis[kk][tx*4];
            const float a[4]  = {av.x, av.y, av.z, av.w};
            const float v1[4] = {b1.x, b1.y, b1.z, b1.w};
            const float vr[4] = {br.x, br.y, br.z, br.w};
            const float vi[4] = {bi.x, bi.y, bi.z, bi.w};
            #pragma unroll
            for (int i = 0; i < 4; ++i)
                #pragma unroll
                for (int j = 0; j < 4; ++j) {
                    acc1[i][j] = fmaf(a[i], v1[j], acc1[i][j]);
                    accr[i][j] = fmaf(a[i], vr[j], accr[i][j]);
                    acci[i][j] = fmaf(a[i], vi[j], acci[i][j]);
                }
        }
        __syncthreads();
    }

    // epilogue
    const int col0 = col_base + tx*4;
    const float4 vb1 = *(const float4*)&bg1[s*D_ + col0];
    const float4 vbr = *(const float4*)&bdr[s*D_ + col0];
    const float4 vbi = *(const float4*)&bdi[s*D_ + col0];
    const float bb1[4] = {vb1.x, vb1.y, vb1.z, vb1.w};
    const float bbr[4] = {vbr.x, vbr.y, vbr.z, vbr.w};
    const float bbi[4] = {vbi.x, vbi.y, vbi.z, vbi.w};

    #pragma unroll
    for (int i = 0; i < 4; ++i) {
        const int row = row_base + ty*4 + i;   // global bt
        float4 o1, orr, oii;
        o1.x = fmaxf(acc1[i][0] + bb1[0], 0.f);
        o1.y = fmaxf(acc1[i][1] + bb1[1], 0.f);
        o1.z = fmaxf(acc1[i][2] + bb1[2], 0.f);
        o1.w = fmaxf(acc1[i][3] + bb1[3], 0.f);
        orr.x = accr[i][0] + bbr[0]; orr.y = accr[i][1] + bbr[1];
        orr.z = accr[i][2] + bbr[2]; orr.w = accr[i][3] + bbr[3];
        oii.x = acci[i][0] + bbi[0]; oii.y = acci[i][1] + bbi[1];
        oii.z = acci[i][2] + bbi[2]; oii.w = acci[i][3] + bbi[3];

        *(float4*)&g1[((size_t)s*BT_ + row)*D_ + col0] = o1;
        float* op = out + (size_t)row*(S_*2*D_) + s*2*D_ + col0;
        *(float4*)op        = orr;   // raw dre
        *(float4*)(op + D_) = oii;   // raw dim
    }
}

// ---------------------------------------------------------------------------
// Kernel 2: gate GEMM over K=256; omg = 1 - sigmoid(logit) = sigmoid(-logit)
// ---------------------------------------------------------------------------
__global__ __launch_bounds__(256) void k2_gate(
    const float* __restrict__ g1,
    const float* __restrict__ Wg2, const float* __restrict__ bg2,
    float* __restrict__ omg)
{
    const int s        = blockIdx.z;
    const int row_base = blockIdx.x * 64;
    const int col_base = blockIdx.y * 64;
    const int tid = threadIdx.x;
    const int tx = tid & 15, ty = tid >> 4;

    __shared__ float gs[16][68];
    __shared__ float ws2[16][64];

    float acc[4][4] = {};

    const size_t wbase = (size_t)s * D_ * D_;
    const size_t gbase = (size_t)s * BT_ * D_;

    for (int k0 = 0; k0 < D_; k0 += 16) {
        {
            const int kk = tid & 15, r = tid >> 4;
            #pragma unroll
            for (int p = 0; p < 4; ++p)
                gs[kk][r + p*16] = g1[gbase + (size_t)(row_base + r + p*16)*D_ + k0 + kk];
        }
        {
            const int dd = tid & 63, kk0 = tid >> 6;
            #pragma unroll
            for (int p = 0; p < 4; ++p) {
                const int kk = kk0 + p*4;
                ws2[kk][dd] = Wg2[wbase + (size_t)(k0 + kk)*D_ + col_base + dd];
            }
        }
        __syncthreads();
        #pragma unroll
        for (int kk = 0; kk < 16; ++kk) {
            const float4 av = *(const float4*)&gs[kk][ty*4];
            const float4 bv = *(const float4*)&ws2[kk][tx*4];
            const float a[4] = {av.x, av.y, av.z, av.w};
            const float v[4] = {bv.x, bv.y, bv.z, bv.w};
            #pragma unroll
            for (int i = 0; i < 4; ++i)
                #pragma unroll
                for (int j = 0; j < 4; ++j)
                    acc[i][j] = fmaf(a[i], v[j], acc[i][j]);
        }
        __syncthreads();
    }

    const int col0 = col_base + tx*4;
    const float4 vb = *(const float4*)&bg2[s*D_ + col0];
    const float bb[4] = {vb.x, vb.y, vb.z, vb.w};
    #pragma unroll
    for (int i = 0; i < 4; ++i) {
        const int row = row_base + ty*4 + i;
        float4 o;
        o.x = 1.f / (1.f + __expf(acc[i][0] + bb[0]));
        o.y = 1.f / (1.f + __expf(acc[i][1] + bb[1]));
        o.z = 1.f / (1.f + __expf(acc[i][2] + bb[2]));
        o.w = 1.f / (1.f + __expf(acc[i][3] + bb[3]));
        *(float4*)&omg[((size_t)s*BT_ + row)*D_ + col0] = o;
    }
}

// ---------------------------------------------------------------------------
// Kernel 3a: per-chunk summaries.  A = prod a_t, H = local scan end (h_-1=0)
// ---------------------------------------------------------------------------
__global__ __launch_bounds__(256) void k3a_chunk(
    const float* __restrict__ omg, const float* __restrict__ out,
    float4* __restrict__ summ, SC sc)
{
    const int blk = blockIdx.x;
    const int c = blk & (CHUNKS-1);
    const int s = (blk / CHUNKS) & (S_-1);
    const int b = blk / (CHUNKS*S_);
    const int d = threadIdx.x;

    const float are = sc.are[s], aim = sc.aim[s], bs = sc.bsc[s];
    float Ar = 1.f, Ai = 0.f, Hr = 0.f, Hi = 0.f;
    const int t0 = c * CL;

    #pragma unroll 4
    for (int t = 0; t < CL; ++t) {
        const int bt = b*T_ + t0 + t;
        const float om = omg[((size_t)s*BT_ + bt)*D_ + d];
        const float* op = out + (size_t)bt*(S_*2*D_) + s*2*D_;
        const float dre = op[d], dim = op[D_ + d];
        const float ar = om*are, ai = om*aim;
        const float ob = om*bs;
        const float br = ob*dre, bi = ob*dim;
        const float nHr = ar*Hr - ai*Hi + br;
        const float nHi = ar*Hi + ai*Hr + bi;
        const float nAr = ar*Ar - ai*Ai;
        const float nAi = ar*Ai + ai*Ar;
        Hr = nHr; Hi = nHi; Ar = nAr; Ai = nAi;
    }
    summ[((size_t)(b*S_ + s)*CHUNKS + c)*D_ + d] = make_float4(Ar, Ai, Hr, Hi);
}

// ---------------------------------------------------------------------------
// Kernel 3b: sequential exclusive scan over chunk summaries per channel.
// Writes the EXCLUSIVE carry (h at end of previous chunk) into summ[].xy.
// ---------------------------------------------------------------------------
__global__ __launch_bounds__(256) void k3b_scan(float4* __restrict__ summ)
{
    const int idx = blockIdx.x*256 + threadIdx.x;     // 0..4095
    const int d = idx & (D_-1);
    const int s = (idx >> 8) & (S_-1);
    const int b = idx >> 10;

    float cr = 0.f, ci = 0.f;
    for (int c = 0; c < CHUNKS; ++c) {
        const size_t off = ((size_t)(b*S_ + s)*CHUNKS + c)*D_ + d;
        const float4 v = summ[off];
        const float ncr = v.x*cr - v.y*ci + v.z;
        const float nci = v.x*ci + v.y*cr + v.w;
        *(float2*)&summ[off] = make_float2(cr, ci);   // exclusive carry
        cr = ncr; ci = nci;
    }
}

// ---------------------------------------------------------------------------
// Kernel 3c: final pass — redo local scan with correct carry, write h.
// ---------------------------------------------------------------------------
__global__ __launch_bounds__(256) void k3c_final(
    const float* __restrict__ omg, float* __restrict__ out,
    const float4* __restrict__ summ, SC sc)
{
    const int blk = blockIdx.x;
    const int c = blk & (CHUNKS-1);
    const int s = (blk / CHUNKS) & (S_-1);
    const int b = blk / (CHUNKS*S_);
    const int d = threadIdx.x;

    const float are = sc.are[s], aim = sc.aim[s], bs = sc.bsc[s];
    const float4 v = summ[((size_t)(b*S_ + s)*CHUNKS + c)*D_ + d];
    float Hr = v.x, Hi = v.y;   // exclusive carry
    const int t0 = c * CL;

    #pragma unroll 4
    for (int t = 0; t < CL; ++t) {
        const int bt = b*T_ + t0 + t;
        const float om = omg[((size_t)s*BT_ + bt)*D_ + d];
        float* op = out + (size_t)bt*(S_*2*D_) + s*2*D_;
        const float dre = op[d], dim = op[D_ + d];
        const float ar = om*are, ai = om*aim;
        const float ob = om*bs;
        const float br = ob*dre, bi = ob*dim;
        const float nHr = ar*Hr - ai*Hi + br;
        const float nHi = ar*Hi + ai*Hr + bi;
        Hr = nHr; Hi = nHi;
        op[d]      = Hr;
        op[D_ + d] = Hi;
    }
}

// ---------------------------------------------------------------------------
extern "C" void kernel_launch(void* const* d_in, const int* in_sizes, int n_in,
                              void* d_out, int out_size, void* d_ws, size_t ws_size,
                              hipStream_t stream)
{
    const float* x   = (const float*)d_in[0];
    const float* Wg1 = (const float*)d_in[1];
    const float* bg1 = (const float*)d_in[2];
    const float* Wg2 = (const float*)d_in[3];
    const float* bg2 = (const float*)d_in[4];
    const float* Wdr = (const float*)d_in[5];
    const float* bdr = (const float*)d_in[6];
    const float* Wdi = (const float*)d_in[7];
    const float* bdi = (const float*)d_in[8];
    float* out = (float*)d_out;

    // workspace layout
    float*  g1   = (float*)d_ws;                       // S*BT*D
    float*  omg  = g1  + (size_t)S_*BT_*D_;            // S*BT*D
    float4* summ = (float4*)(omg + (size_t)S_*BT_*D_); // B*S*CHUNKS*D float4s

    // scale constants (match np.linspace in float64, then cast)
    SC sc;
    {
        const double r[S_]  = {1.0, 0.999, 0.9495, 0.9};
        const double th[S_] = {0.0, 0.01, 0.505, 1.0};
        for (int s = 0; s < S_; ++s) {
            sc.are[s] = (float)(r[s] * cos(th[s]));
            sc.aim[s] = (float)(r[s] * sin(th[s]));
            sc.bsc[s] = (r[s] >= 1.0) ? (float)(1.0/16.0) : (float)(1.0 - r[s]);
        }
    }

    dim3 gemm_grid(BT_/64, D_/64, S_);
    k1_gemm3<<<gemm_grid, 256, 0, stream>>>(x, Wg1, bg1, Wdr, bdr, Wdi, bdi, g1, out);
    k2_gate <<<gemm_grid, 256, 0, stream>>>(g1, Wg2, bg2, omg);
    k3a_chunk<<<B_*S_*CHUNKS, 256, 0, stream>>>(omg, out, summ, sc);
    k3b_scan <<<(B_*S_*D_)/256, 256, 0, stream>>>(summ);
    k3c_final<<<B_*S_*CHUNKS, 256, 0, stream>>>(omg, out, summ, sc);
}

// Round 2
// 473.666 us; speedup vs baseline: 3.2424x; 3.2424x over previous
//
#include <hip/hip_runtime.h>
#include <cmath>

#define S_   4
#define DIN  1024
#define D_   256
#define B_   4
#define T_   4096
#define BT_  (B_*T_)
#define GN   (S_*3*D_)     // 3072 concat N for the big GEMM
#define CHUNKS 128
#define CL   (T_/CHUNKS)   // 32

typedef short bf16x8 __attribute__((ext_vector_type(8)));
typedef float f32x4  __attribute__((ext_vector_type(4)));

struct SC { float are[S_]; float aim[S_]; float bsc[S_]; };

__device__ inline unsigned short f2bf(float f) {
    unsigned int u = __builtin_bit_cast(unsigned int, f);
    unsigned int r = (u + 0x7FFFu + ((u >> 16) & 1u)) >> 16;
    return (unsigned short)r;
}

#define GLD_LDS(gp, lp) \
    __builtin_amdgcn_global_load_lds( \
        (const __attribute__((address_space(1))) void*)(gp), \
        (__attribute__((address_space(3))) void*)(lp), 16, 0, 0)

// ---------------------------------------------------------------------------
// x fp32 -> bf16 (row-major [BT][DIN] unchanged layout)
// ---------------------------------------------------------------------------
__global__ __launch_bounds__(256) void kconv_x(
    const float* __restrict__ x, unsigned short* __restrict__ xb)
{
    const size_t i = ((size_t)blockIdx.x*256 + threadIdx.x)*4;
    const float4 v = *(const float4*)(x + i);
    ushort4 o;
    o.x = f2bf(v.x); o.y = f2bf(v.y); o.z = f2bf(v.z); o.w = f2bf(v.w);
    *(ushort4*)(xb + i) = o;
}

// ---------------------------------------------------------------------------
// Weight transpose+convert: src [S][K][N] fp32 -> dst [S-strided][N][K] bf16
// ---------------------------------------------------------------------------
__global__ __launch_bounds__(256) void kconv_w(
    const float* __restrict__ src, unsigned short* __restrict__ dst,
    int K, int N, size_t dst_s_stride)
{
    __shared__ float t[32][33];
    const int k0 = blockIdx.x*32, n0 = blockIdx.y*32, s = blockIdx.z;
    const float* sp = src + (size_t)s*K*N;
    unsigned short* dp = dst + (size_t)s*dst_s_stride;
    const int c = threadIdx.x & 31, r0 = threadIdx.x >> 5;   // r0: 0..7
    #pragma unroll
    for (int p = 0; p < 4; ++p)
        t[r0 + p*8][c] = sp[(size_t)(k0 + r0 + p*8)*N + n0 + c];
    __syncthreads();
    #pragma unroll
    for (int p = 0; p < 4; ++p)
        dp[(size_t)(n0 + r0 + p*8)*K + k0 + c] = f2bf(t[c][r0 + p*8]);
}

// ---------------------------------------------------------------------------
// k1: C[16384][3072] = xb[16384][1024] * Bct[3072][1024]^T  (bf16 MFMA)
// 128x128 tile, BK=64, 4 waves each 64x64 (4x4 MFMA 16x16x32).
// Epilogue per column-tile: mat0 -> g1 bf16 (bias+relu), mat1/2 -> drives fp32.
// ---------------------------------------------------------------------------
__global__ __launch_bounds__(256) void k1_mfma(
    const unsigned short* __restrict__ xb,
    const unsigned short* __restrict__ Bct,
    const float* __restrict__ bg1, const float* __restrict__ bdr,
    const float* __restrict__ bdi,
    unsigned short* __restrict__ g1b, float* __restrict__ out)
{
    __shared__ unsigned short As[128*64];
    __shared__ unsigned short Bs[128*64];

    const int tid = threadIdx.x;
    const int wave = tid >> 6, lane = tid & 63;
    const int wm = (wave >> 1) * 64, wn = (wave & 1) * 64;
    const int row0 = blockIdx.x * 128, col0 = blockIdx.y * 128;

    const f32x4 z = {0.f, 0.f, 0.f, 0.f};
    f32x4 acc[4][4];
    #pragma unroll
    for (int i = 0; i < 4; ++i)
        #pragma unroll
        for (int j = 0; j < 4; ++j) acc[i][j] = z;

    const unsigned short* Ag = xb  + (size_t)row0*DIN;
    const unsigned short* Bg = Bct + (size_t)col0*DIN;
    const int lrow = lane >> 3;          // 0..7
    const int lk   = (lane & 7) * 8;     // k elem offset
    const int cn   = lane & 15, quad = lane >> 4;

    for (int k0 = 0; k0 < DIN; k0 += 64) {
        #pragma unroll
        for (int t = 0; t < 4; ++t) {
            const int m0 = wave*32 + t*8;
            GLD_LDS(Ag + (size_t)(m0 + lrow)*DIN + k0 + lk, As + m0*64);
            GLD_LDS(Bg + (size_t)(m0 + lrow)*DIN + k0 + lk, Bs + m0*64);
        }
        __syncthreads();
        #pragma unroll
        for (int ks = 0; ks < 2; ++ks) {
            const int kb = ks*32 + quad*8;
            bf16x8 af[4], bfv[4];
            #pragma unroll
            for (int i = 0; i < 4; ++i)
                af[i] = *(const bf16x8*)(As + (wm + i*16 + cn)*64 + kb);
            #pragma unroll
            for (int j = 0; j < 4; ++j)
                bfv[j] = *(const bf16x8*)(Bs + (wn + j*16 + cn)*64 + kb);
            #pragma unroll
            for (int i = 0; i < 4; ++i)
                #pragma unroll
                for (int j = 0; j < 4; ++j)
                    acc[i][j] = __builtin_amdgcn_mfma_f32_16x16x32_bf16(
                        af[i], bfv[j], acc[i][j], 0, 0, 0);
        }
        __syncthreads();
    }

    // epilogue — (s, mat) are block-uniform
    const int s    = col0 / 768;
    const int rem  = col0 - s*768;
    const int mat  = rem >> 8;                 // 0:g1  1:dre  2:dim
    const int dbase = (rem & 255) + wn + cn;
    const float* bias = (mat == 0) ? bg1 : ((mat == 1) ? bdr : bdi);
    float bv[4];
    #pragma unroll
    for (int j = 0; j < 4; ++j) bv[j] = bias[s*D_ + dbase + j*16];

    const int qr = quad * 4;
    #pragma unroll
    for (int i = 0; i < 4; ++i) {
        const int m = row0 + wm + i*16 + qr;
        #pragma unroll
        for (int j = 0; j < 4; ++j) {
            const int d = dbase + j*16;
            const f32x4 v = acc[i][j];
            if (mat == 0) {
                unsigned short* gp = g1b + ((size_t)s*BT_ + m)*D_ + d;
                #pragma unroll
                for (int r = 0; r < 4; ++r)
                    gp[(size_t)r*D_] = f2bf(fmaxf(v[r] + bv[j], 0.f));
            } else {
                float* op = out + (size_t)m*(S_*2*D_) + s*2*D_
                          + (mat == 2 ? D_ : 0) + d;
                #pragma unroll
                for (int r = 0; r < 4; ++r)
                    op[(size_t)r*(S_*2*D_)] = v[r] + bv[j];
            }
        }
    }
}

// ---------------------------------------------------------------------------
// k2: per-s  omg = sigmoid(-(g1 @ Wg2 + bg2));  M=16384 N=256 K=256 bf16 MFMA
// ---------------------------------------------------------------------------
__global__ __launch_bounds__(256) void k2_mfma(
    const unsigned short* __restrict__ g1b,
    const unsigned short* __restrict__ B2t,
    const float* __restrict__ bg2, float* __restrict__ omg)
{
    __shared__ unsigned short As[128*64];
    __shared__ unsigned short Bs[128*64];

    const int tid = threadIdx.x;
    const int wave = tid >> 6, lane = tid & 63;
    const int wm = (wave >> 1) * 64, wn = (wave & 1) * 64;
    const int row0 = blockIdx.x * 128, col0 = blockIdx.y * 128;
    const int s = blockIdx.z;

    const f32x4 z = {0.f, 0.f, 0.f, 0.f};
    f32x4 acc[4][4];
    #pragma unroll
    for (int i = 0; i < 4; ++i)
        #pragma unroll
        for (int j = 0; j < 4; ++j) acc[i][j] = z;

    const unsigned short* Ag = g1b + ((size_t)s*BT_ + row0)*D_;
    const unsigned short* Bg = B2t + (size_t)s*D_*D_ + (size_t)col0*D_;
    const int lrow = lane >> 3;
    const int lk   = (lane & 7) * 8;
    const int cn   = lane & 15, quad = lane >> 4;

    for (int k0 = 0; k0 < D_; k0 += 64) {
        #pragma unroll
        for (int t = 0; t < 4; ++t) {
            const int m0 = wave*32 + t*8;
            GLD_LDS(Ag + (size_t)(m0 + lrow)*D_ + k0 + lk, As + m0*64);
            GLD_LDS(Bg + (size_t)(m0 + lrow)*D_ + k0 + lk, Bs + m0*64);
        }
        __syncthreads();
        #pragma unroll
        for (int ks = 0; ks < 2; ++ks) {
            const int kb = ks*32 + quad*8;
            bf16x8 af[4], bfv[4];
            #pragma unroll
            for (int i = 0; i < 4; ++i)
                af[i] = *(const bf16x8*)(As + (wm + i*16 + cn)*64 + kb);
            #pragma unroll
            for (int j = 0; j < 4; ++j)
                bfv[j] = *(const bf16x8*)(Bs + (wn + j*16 + cn)*64 + kb);
            #pragma unroll
            for (int i = 0; i < 4; ++i)
                #pragma unroll
                for (int j = 0; j < 4; ++j)
                    acc[i][j] = __builtin_amdgcn_mfma_f32_16x16x32_bf16(
                        af[i], bfv[j], acc[i][j], 0, 0, 0);
        }
        __syncthreads();
    }

    const int qr = quad * 4;
    float bv[4];
    #pragma unroll
    for (int j = 0; j < 4; ++j) bv[j] = bg2[s*D_ + col0 + wn + j*16 + cn];

    #pragma unroll
    for (int i = 0; i < 4; ++i) {
        const int m = row0 + wm + i*16 + qr;
        #pragma unroll
        for (int j = 0; j < 4; ++j) {
            const int d = col0 + wn + j*16 + cn;
            const f32x4 v = acc[i][j];
            float* op = omg + ((size_t)s*BT_ + m)*D_ + d;
            #pragma unroll
            for (int r = 0; r < 4; ++r)
                op[(size_t)r*D_] = 1.f / (1.f + __expf(v[r] + bv[j]));
        }
    }
}

// ---------------------------------------------------------------------------
// Kernel 3a: per-chunk summaries.  A = prod a_t, H = local scan end (h_-1=0)
// ---------------------------------------------------------------------------
__global__ __launch_bounds__(256) void k3a_chunk(
    const float* __restrict__ omg, const float* __restrict__ out,
    float4* __restrict__ summ, SC sc)
{
    const int blk = blockIdx.x;
    const int c = blk & (CHUNKS-1);
    const int s = (blk / CHUNKS) & (S_-1);
    const int b = blk / (CHUNKS*S_);
    const int d = threadIdx.x;

    const float are = sc.are[s], aim = sc.aim[s], bs = sc.bsc[s];
    float Ar = 1.f, Ai = 0.f, Hr = 0.f, Hi = 0.f;
    const int t0 = c * CL;

    #pragma unroll 4
    for (int t = 0; t < CL; ++t) {
        const int bt = b*T_ + t0 + t;
        const float om = omg[((size_t)s*BT_ + bt)*D_ + d];
        const float* op = out + (size_t)bt*(S_*2*D_) + s*2*D_;
        const float dre = op[d], dim = op[D_ + d];
        const float ar = om*are, ai = om*aim;
        const float ob = om*bs;
        const float br = ob*dre, bi = ob*dim;
        const float nHr = ar*Hr - ai*Hi + br;
        const float nHi = ar*Hi + ai*Hr + bi;
        const float nAr = ar*Ar - ai*Ai;
        const float nAi = ar*Ai + ai*Ar;
        Hr = nHr; Hi = nHi; Ar = nAr; Ai = nAi;
    }
    summ[((size_t)(b*S_ + s)*CHUNKS + c)*D_ + d] = make_float4(Ar, Ai, Hr, Hi);
}

// ---------------------------------------------------------------------------
// Kernel 3b: sequential exclusive scan over chunk summaries per channel.
// ---------------------------------------------------------------------------
__global__ __launch_bounds__(256) void k3b_scan(float4* __restrict__ summ)
{
    const int idx = blockIdx.x*256 + threadIdx.x;     // 0..4095
    const int d = idx & (D_-1);
    const int s = (idx >> 8) & (S_-1);
    const int b = idx >> 10;

    float cr = 0.f, ci = 0.f;
    for (int c = 0; c < CHUNKS; ++c) {
        const size_t off = ((size_t)(b*S_ + s)*CHUNKS + c)*D_ + d;
        const float4 v = summ[off];
        const float ncr = v.x*cr - v.y*ci + v.z;
        const float nci = v.x*ci + v.y*cr + v.w;
        *(float2*)&summ[off] = make_float2(cr, ci);   // exclusive carry
        cr = ncr; ci = nci;
    }
}

// ---------------------------------------------------------------------------
// Kernel 3c: final pass — redo local scan with correct carry, write h.
// ---------------------------------------------------------------------------
__global__ __launch_bounds__(256) void k3c_final(
    const float* __restrict__ omg, float* __restrict__ out,
    const float4* __restrict__ summ, SC sc)
{
    const int blk = blockIdx.x;
    const int c = blk & (CHUNKS-1);
    const int s = (blk / CHUNKS) & (S_-1);
    const int b = blk / (CHUNKS*S_);
    const int d = threadIdx.x;

    const float are = sc.are[s], aim = sc.aim[s], bs = sc.bsc[s];
    const float4 v = summ[((size_t)(b*S_ + s)*CHUNKS + c)*D_ + d];
    float Hr = v.x, Hi = v.y;   // exclusive carry
    const int t0 = c * CL;

    #pragma unroll 4
    for (int t = 0; t < CL; ++t) {
        const int bt = b*T_ + t0 + t;
        const float om = omg[((size_t)s*BT_ + bt)*D_ + d];
        float* op = out + (size_t)bt*(S_*2*D_) + s*2*D_;
        const float dre = op[d], dim = op[D_ + d];
        const float ar = om*are, ai = om*aim;
        const float ob = om*bs;
        const float br = ob*dre, bi = ob*dim;
        const float nHr = ar*Hr - ai*Hi + br;
        const float nHi = ar*Hi + ai*Hr + bi;
        Hr = nHr; Hi = nHi;
        op[d]      = Hr;
        op[D_ + d] = Hi;
    }
}

// ---------------------------------------------------------------------------
extern "C" void kernel_launch(void* const* d_in, const int* in_sizes, int n_in,
                              void* d_out, int out_size, void* d_ws, size_t ws_size,
                              hipStream_t stream)
{
    const float* x   = (const float*)d_in[0];
    const float* Wg1 = (const float*)d_in[1];
    const float* bg1 = (const float*)d_in[2];
    const float* Wg2 = (const float*)d_in[3];
    const float* bg2 = (const float*)d_in[4];
    const float* Wdr = (const float*)d_in[5];
    const float* bdr = (const float*)d_in[6];
    const float* Wdi = (const float*)d_in[7];
    const float* bdi = (const float*)d_in[8];
    float* out = (float*)d_out;

    // workspace layout (xb aliases omg: xb dead before k2 writes omg)
    char* ws = (char*)d_ws;
    float4*         summ = (float4*)ws;                         // 33,554,432 B
    float*          omg  = (float*)(ws + 33554432);             // 67,108,864 B
    unsigned short* xb   = (unsigned short*)omg;                // 33.5 MB alias
    unsigned short* g1b  = (unsigned short*)(ws + 33554432 + 67108864); // 33,554,432 B
    unsigned short* Bct  = g1b + (size_t)S_*BT_*D_;             // 6,291,456 B
    unsigned short* B2t  = Bct + (size_t)GN*DIN;                // 524,288 B

    SC sc;
    {
        const double r[S_]  = {1.0, 0.999, 0.9495, 0.9};
        const double th[S_] = {0.0, 0.01, 0.505, 1.0};
        for (int s = 0; s < S_; ++s) {
            sc.are[s] = (float)(r[s] * cos(th[s]));
            sc.aim[s] = (float)(r[s] * sin(th[s]));
            sc.bsc[s] = (r[s] >= 1.0) ? (float)(1.0/16.0) : (float)(1.0 - r[s]);
        }
    }

    // conversions
    kconv_x<<<(BT_*DIN)/1024, 256, 0, stream>>>(x, xb);
    // Bct layout: [s][mat][256][1024]; per-tensor dst offset = mat*256*1024
    kconv_w<<<dim3(32,8,S_), 256, 0, stream>>>(Wg1, Bct + 0*D_*DIN, DIN, D_, (size_t)768*DIN);
    kconv_w<<<dim3(32,8,S_), 256, 0, stream>>>(Wdr, Bct + 1*D_*DIN, DIN, D_, (size_t)768*DIN);
    kconv_w<<<dim3(32,8,S_), 256, 0, stream>>>(Wdi, Bct + 2*D_*DIN, DIN, D_, (size_t)768*DIN);
    kconv_w<<<dim3(8,8,S_),  256, 0, stream>>>(Wg2, B2t, D_, D_, (size_t)D_*D_);

    // GEMMs
    k1_mfma<<<dim3(BT_/128, GN/128), 256, 0, stream>>>(xb, Bct, bg1, bdr, bdi, g1b, out);
    k2_mfma<<<dim3(BT_/128, D_/128, S_), 256, 0, stream>>>(g1b, B2t, bg2, omg);

    // scan
    k3a_chunk<<<B_*S_*CHUNKS, 256, 0, stream>>>(omg, out, summ, sc);
    k3b_scan <<<(B_*S_*D_)/256, 256, 0, stream>>>(summ);
    k3c_final<<<B_*S_*CHUNKS, 256, 0, stream>>>(omg, out, summ, sc);
}

// Round 4
// 437.394 us; speedup vs baseline: 3.5113x; 1.0829x over previous
//
#include <hip/hip_runtime.h>
#include <cmath>

#define S_   4
#define DIN  1024
#define D_   256
#define B_   4
#define T_   4096
#define BT_  (B_*T_)
#define GN   (S_*3*D_)     // 3072 concat N for the big GEMM
#define CHUNKS 128
#define CL   (T_/CHUNKS)   // 32

typedef short bf16x8 __attribute__((ext_vector_type(8)));
typedef float f32x4  __attribute__((ext_vector_type(4)));

struct SC { float are[S_]; float aim[S_]; float bsc[S_]; };

__device__ inline unsigned short f2bf(float f) {
    unsigned int u = __builtin_bit_cast(unsigned int, f);
    unsigned int r = (u + 0x7FFFu + ((u >> 16) & 1u)) >> 16;
    return (unsigned short)r;
}
__device__ inline float bf2f_lo(unsigned int u) {
    return __builtin_bit_cast(float, u << 16);
}
__device__ inline float bf2f_hi(unsigned int u) {
    return __builtin_bit_cast(float, u & 0xFFFF0000u);
}
// omg u16 fixed-point decode: (u + 0.5) / 65536
__device__ inline float u16om(unsigned int u) {
    return ((float)u + 0.5f) * (1.f/65536.f);
}

#define GLD_LDS(gp, lp) \
    __builtin_amdgcn_global_load_lds( \
        (const __attribute__((address_space(1))) void*)(gp), \
        (__attribute__((address_space(3))) void*)(lp), 16, 0, 0)

// ---------------------------------------------------------------------------
// x fp32 -> bf16
// ---------------------------------------------------------------------------
__global__ __launch_bounds__(256) void kconv_x(
    const float* __restrict__ x, unsigned short* __restrict__ xb)
{
    const size_t i = ((size_t)blockIdx.x*256 + threadIdx.x)*4;
    const float4 v = *(const float4*)(x + i);
    ushort4 o;
    o.x = f2bf(v.x); o.y = f2bf(v.y); o.z = f2bf(v.z); o.w = f2bf(v.w);
    *(ushort4*)(xb + i) = o;
}

// ---------------------------------------------------------------------------
// Weight transpose+convert: src [S][K][N] fp32 -> dst [S-strided][N][K] bf16
// ---------------------------------------------------------------------------
__global__ __launch_bounds__(256) void kconv_w(
    const float* __restrict__ src, unsigned short* __restrict__ dst,
    int K, int N, size_t dst_s_stride)
{
    __shared__ float t[32][33];
    const int k0 = blockIdx.x*32, n0 = blockIdx.y*32, s = blockIdx.z;
    const float* sp = src + (size_t)s*K*N;
    unsigned short* dp = dst + (size_t)s*dst_s_stride;
    const int c = threadIdx.x & 31, r0 = threadIdx.x >> 5;
    #pragma unroll
    for (int p = 0; p < 4; ++p)
        t[r0 + p*8][c] = sp[(size_t)(k0 + r0 + p*8)*N + n0 + c];
    __syncthreads();
    #pragma unroll
    for (int p = 0; p < 4; ++p)
        dp[(size_t)(n0 + r0 + p*8)*K + k0 + c] = f2bf(t[c][r0 + p*8]);
}

// ---------------------------------------------------------------------------
// k1: C[16384][3072] = xb * Bct^T (bf16 MFMA), 128x128 tile, BK=64.
// LDS XOR-swizzled (src chunk c^row, reader chunk (ks*4+quad)^(cn&7)).
// Epilogue: mat0 -> g1 bf16 (bias+relu); mat1/2 -> drives (bf16 ws or fp32 out)
// ---------------------------------------------------------------------------
template<bool DRVB>
__global__ __launch_bounds__(256) void k1_mfma(
    const unsigned short* __restrict__ xb,
    const unsigned short* __restrict__ Bct,
    const float* __restrict__ bg1, const float* __restrict__ bdr,
    const float* __restrict__ bdi,
    unsigned short* __restrict__ g1b,
    unsigned short* __restrict__ drvb, float* __restrict__ drvf)
{
    __shared__ unsigned short As[128*64];
    __shared__ unsigned short Bs[128*64];

    const int tid = threadIdx.x;
    const int wave = tid >> 6, lane = tid & 63;
    const int wm = (wave >> 1) * 64, wn = (wave & 1) * 64;
    const int row0 = blockIdx.x * 128, col0 = blockIdx.y * 128;

    const f32x4 z = {0.f, 0.f, 0.f, 0.f};
    f32x4 acc[4][4];
    #pragma unroll
    for (int i = 0; i < 4; ++i)
        #pragma unroll
        for (int j = 0; j < 4; ++j) acc[i][j] = z;

    const unsigned short* Ag = xb  + (size_t)row0*DIN;
    const unsigned short* Bg = Bct + (size_t)col0*DIN;
    const int lrow = lane >> 3;                     // 0..7
    const int lksw = ((lane & 7) ^ lrow) * 8;       // swizzled src k offset
    const int cn   = lane & 15, quad = lane >> 4;
    const int e    = cn & 7;                        // reader swizzle key

    for (int k0 = 0; k0 < DIN; k0 += 64) {
        #pragma unroll
        for (int t = 0; t < 4; ++t) {
            const int m0 = wave*32 + t*8;
            GLD_LDS(Ag + (size_t)(m0 + lrow)*DIN + k0 + lksw, As + m0*64);
            GLD_LDS(Bg + (size_t)(m0 + lrow)*DIN + k0 + lksw, Bs + m0*64);
        }
        __syncthreads();
        #pragma unroll
        for (int ks = 0; ks < 2; ++ks) {
            const int offs = (((ks*4 + quad) ^ e)) * 8;
            bf16x8 af[4], bfv[4];
            #pragma unroll
            for (int i = 0; i < 4; ++i)
                af[i] = *(const bf16x8*)(As + (wm + i*16 + cn)*64 + offs);
            #pragma unroll
            for (int j = 0; j < 4; ++j)
                bfv[j] = *(const bf16x8*)(Bs + (wn + j*16 + cn)*64 + offs);
            #pragma unroll
            for (int i = 0; i < 4; ++i)
                #pragma unroll
                for (int j = 0; j < 4; ++j)
                    acc[i][j] = __builtin_amdgcn_mfma_f32_16x16x32_bf16(
                        af[i], bfv[j], acc[i][j], 0, 0, 0);
        }
        __syncthreads();
    }

    // epilogue — (s, mat) are block-uniform
    const int s    = col0 / 768;
    const int rem  = col0 - s*768;
    const int mat  = rem >> 8;                 // 0:g1  1:dre  2:dim
    const int dbase = (rem & 255) + wn + cn;
    const float* bias = (mat == 0) ? bg1 : ((mat == 1) ? bdr : bdi);
    float bv[4];
    #pragma unroll
    for (int j = 0; j < 4; ++j) bv[j] = bias[s*D_ + dbase + j*16];

    const int qr = quad * 4;
    #pragma unroll
    for (int i = 0; i < 4; ++i) {
        const int m = row0 + wm + i*16 + qr;
        #pragma unroll
        for (int j = 0; j < 4; ++j) {
            const int d = dbase + j*16;
            const f32x4 v = acc[i][j];
            if (mat == 0) {
                unsigned short* gp = g1b + ((size_t)s*BT_ + m)*D_ + d;
                #pragma unroll
                for (int r = 0; r < 4; ++r)
                    gp[(size_t)r*D_] = f2bf(fmaxf(v[r] + bv[j], 0.f));
            } else {
                const size_t base = (size_t)m*(S_*2*D_) + s*2*D_
                                  + (mat == 2 ? D_ : 0) + d;
                if (DRVB) {
                    #pragma unroll
                    for (int r = 0; r < 4; ++r)
                        drvb[base + (size_t)r*(S_*2*D_)] = f2bf(v[r] + bv[j]);
                } else {
                    #pragma unroll
                    for (int r = 0; r < 4; ++r)
                        drvf[base + (size_t)r*(S_*2*D_)] = v[r] + bv[j];
                }
            }
        }
    }
}

// ---------------------------------------------------------------------------
// k2: per-s  omg = sigmoid(-(g1 @ Wg2 + bg2)) -> u16 fixed-point
// ---------------------------------------------------------------------------
__global__ __launch_bounds__(256) void k2_mfma(
    const unsigned short* __restrict__ g1b,
    const unsigned short* __restrict__ B2t,
    const float* __restrict__ bg2, unsigned short* __restrict__ omgu)
{
    __shared__ unsigned short As[128*64];
    __shared__ unsigned short Bs[128*64];

    const int tid = threadIdx.x;
    const int wave = tid >> 6, lane = tid & 63;
    const int wm = (wave >> 1) * 64, wn = (wave & 1) * 64;
    const int row0 = blockIdx.x * 128, col0 = blockIdx.y * 128;
    const int s = blockIdx.z;

    const f32x4 z = {0.f, 0.f, 0.f, 0.f};
    f32x4 acc[4][4];
    #pragma unroll
    for (int i = 0; i < 4; ++i)
        #pragma unroll
        for (int j = 0; j < 4; ++j) acc[i][j] = z;

    const unsigned short* Ag = g1b + ((size_t)s*BT_ + row0)*D_;
    const unsigned short* Bg = B2t + (size_t)s*D_*D_ + (size_t)col0*D_;
    const int lrow = lane >> 3;
    const int lksw = ((lane & 7) ^ lrow) * 8;
    const int cn   = lane & 15, quad = lane >> 4;
    const int e    = cn & 7;

    for (int k0 = 0; k0 < D_; k0 += 64) {
        #pragma unroll
        for (int t = 0; t < 4; ++t) {
            const int m0 = wave*32 + t*8;
            GLD_LDS(Ag + (size_t)(m0 + lrow)*D_ + k0 + lksw, As + m0*64);
            GLD_LDS(Bg + (size_t)(m0 + lrow)*D_ + k0 + lksw, Bs + m0*64);
        }
        __syncthreads();
        #pragma unroll
        for (int ks = 0; ks < 2; ++ks) {
            const int offs = (((ks*4 + quad) ^ e)) * 8;
            bf16x8 af[4], bfv[4];
            #pragma unroll
            for (int i = 0; i < 4; ++i)
                af[i] = *(const bf16x8*)(As + (wm + i*16 + cn)*64 + offs);
            #pragma unroll
            for (int j = 0; j < 4; ++j)
                bfv[j] = *(const bf16x8*)(Bs + (wn + j*16 + cn)*64 + offs);
            #pragma unroll
            for (int i = 0; i < 4; ++i)
                #pragma unroll
                for (int j = 0; j < 4; ++j)
                    acc[i][j] = __builtin_amdgcn_mfma_f32_16x16x32_bf16(
                        af[i], bfv[j], acc[i][j], 0, 0, 0);
        }
        __syncthreads();
    }

    const int qr = quad * 4;
    float bv[4];
    #pragma unroll
    for (int j = 0; j < 4; ++j) bv[j] = bg2[s*D_ + col0 + wn + j*16 + cn];

    #pragma unroll
    for (int i = 0; i < 4; ++i) {
        const int m = row0 + wm + i*16 + qr;
        #pragma unroll
        for (int j = 0; j < 4; ++j) {
            const int d = col0 + wn + j*16 + cn;
            const f32x4 v = acc[i][j];
            unsigned short* op = omgu + ((size_t)s*BT_ + m)*D_ + d;
            #pragma unroll
            for (int r = 0; r < 4; ++r) {
                const float om = 1.f / (1.f + __expf(v[r] + bv[j]));
                op[(size_t)r*D_] =
                    (unsigned short)fminf(om * 65536.f, 65535.f);
            }
        }
    }
}

// ---------------------------------------------------------------------------
// k3a: per-chunk summaries. 128 threads, 2 channels each, packed loads.
// ---------------------------------------------------------------------------
template<bool DRVB>
__global__ __launch_bounds__(128) void k3a_chunk(
    const unsigned short* __restrict__ omgu,
    const unsigned short* __restrict__ drvb, const float* __restrict__ drvf,
    float4* __restrict__ summ, SC sc)
{
    const int blk = blockIdx.x;
    const int c = blk & (CHUNKS-1);
    const int s = (blk >> 7) & (S_-1);
    const int b = blk >> 9;
    const int d2 = threadIdx.x;     // channels 2*d2, 2*d2+1

    const float are = sc.are[s], aim = sc.aim[s], bs = sc.bsc[s];
    float Ar[2] = {1.f,1.f}, Ai[2] = {0,0}, Hr[2] = {0,0}, Hi[2] = {0,0};
    const int t0 = c * CL;

    #pragma unroll 4
    for (int t = 0; t < CL; ++t) {
        const int bt = b*T_ + t0 + t;
        const unsigned int ov =
            *(const unsigned int*)(omgu + ((size_t)s*BT_ + bt)*D_ + 2*d2);
        const float om[2] = { u16om(ov & 0xFFFFu), u16om(ov >> 16) };
        const size_t base = (size_t)bt*(S_*2*D_) + s*2*D_ + 2*d2;
        float dre[2], dim[2];
        if (DRVB) {
            const unsigned int ur = *(const unsigned int*)(drvb + base);
            const unsigned int ui = *(const unsigned int*)(drvb + base + D_);
            dre[0] = bf2f_lo(ur); dre[1] = bf2f_hi(ur);
            dim[0] = bf2f_lo(ui); dim[1] = bf2f_hi(ui);
        } else {
            const float2 fr = *(const float2*)(drvf + base);
            const float2 fi = *(const float2*)(drvf + base + D_);
            dre[0] = fr.x; dre[1] = fr.y; dim[0] = fi.x; dim[1] = fi.y;
        }
        #pragma unroll
        for (int u = 0; u < 2; ++u) {
            const float ar = om[u]*are, ai = om[u]*aim, ob = om[u]*bs;
            const float br = ob*dre[u], bi = ob*dim[u];
            const float nHr = ar*Hr[u] - ai*Hi[u] + br;
            const float nHi = ar*Hi[u] + ai*Hr[u] + bi;
            const float nAr = ar*Ar[u] - ai*Ai[u];
            const float nAi = ar*Ai[u] + ai*Ar[u];
            Hr[u]=nHr; Hi[u]=nHi; Ar[u]=nAr; Ai[u]=nAi;
        }
    }
    const size_t so = ((size_t)(b*S_ + s)*CHUNKS + c)*D_ + 2*d2;
    summ[so]     = make_float4(Ar[0], Ai[0], Hr[0], Hi[0]);
    summ[so + 1] = make_float4(Ar[1], Ai[1], Hr[1], Hi[1]);
}

// ---------------------------------------------------------------------------
// k3b: sequential exclusive scan over chunk summaries per channel.
// ---------------------------------------------------------------------------
__global__ __launch_bounds__(256) void k3b_scan(float4* __restrict__ summ)
{
    const int idx = blockIdx.x*256 + threadIdx.x;     // 0..4095
    const int d = idx & (D_-1);
    const int s = (idx >> 8) & (S_-1);
    const int b = idx >> 10;

    float cr = 0.f, ci = 0.f;
    for (int c = 0; c < CHUNKS; ++c) {
        const size_t off = ((size_t)(b*S_ + s)*CHUNKS + c)*D_ + d;
        const float4 v = summ[off];
        const float ncr = v.x*cr - v.y*ci + v.z;
        const float nci = v.x*ci + v.y*cr + v.w;
        *(float2*)&summ[off] = make_float2(cr, ci);   // exclusive carry
        cr = ncr; ci = nci;
    }
}

// ---------------------------------------------------------------------------
// k3c: final pass — redo local scan with carry, write h (fp32) to out.
// ---------------------------------------------------------------------------
template<bool DRVB>
__global__ __launch_bounds__(128) void k3c_final(
    const unsigned short* __restrict__ omgu,
    const unsigned short* __restrict__ drvb, const float* __restrict__ drvf,
    float* __restrict__ out, const float4* __restrict__ summ, SC sc)
{
    const int blk = blockIdx.x;
    const int c = blk & (CHUNKS-1);
    const int s = (blk >> 7) & (S_-1);
    const int b = blk >> 9;
    const int d2 = threadIdx.x;

    const float are = sc.are[s], aim = sc.aim[s], bs = sc.bsc[s];
    const size_t so = ((size_t)(b*S_ + s)*CHUNKS + c)*D_ + 2*d2;
    const float4 v0 = summ[so];
    const float4 v1 = summ[so + 1];
    float Hr[2] = {v0.x, v1.x}, Hi[2] = {v0.y, v1.y};
    const int t0 = c * CL;

    #pragma unroll 4
    for (int t = 0; t < CL; ++t) {
        const int bt = b*T_ + t0 + t;
        const unsigned int ov =
            *(const unsigned int*)(omgu + ((size_t)s*BT_ + bt)*D_ + 2*d2);
        const float om[2] = { u16om(ov & 0xFFFFu), u16om(ov >> 16) };
        const size_t base = (size_t)bt*(S_*2*D_) + s*2*D_ + 2*d2;
        float dre[2], dim[2];
        if (DRVB) {
            const unsigned int ur = *(const unsigned int*)(drvb + base);
            const unsigned int ui = *(const unsigned int*)(drvb + base + D_);
            dre[0] = bf2f_lo(ur); dre[1] = bf2f_hi(ur);
            dim[0] = bf2f_lo(ui); dim[1] = bf2f_hi(ui);
        } else {
            const float2 fr = *(const float2*)(drvf + base);
            const float2 fi = *(const float2*)(drvf + base + D_);
            dre[0] = fr.x; dre[1] = fr.y; dim[0] = fi.x; dim[1] = fi.y;
        }
        #pragma unroll
        for (int u = 0; u < 2; ++u) {
            const float ar = om[u]*are, ai = om[u]*aim, ob = om[u]*bs;
            const float br = ob*dre[u], bi = ob*dim[u];
            const float nHr = ar*Hr[u] - ai*Hi[u] + br;
            const float nHi = ar*Hi[u] + ai*Hr[u] + bi;
            Hr[u]=nHr; Hi[u]=nHi;
        }
        *(float2*)(out + base)      = make_float2(Hr[0], Hr[1]);
        *(float2*)(out + base + D_) = make_float2(Hi[0], Hi[1]);
    }
}

// ---------------------------------------------------------------------------
extern "C" void kernel_launch(void* const* d_in, const int* in_sizes, int n_in,
                              void* d_out, int out_size, void* d_ws, size_t ws_size,
                              hipStream_t stream)
{
    const float* x   = (const float*)d_in[0];
    const float* Wg1 = (const float*)d_in[1];
    const float* bg1 = (const float*)d_in[2];
    const float* Wg2 = (const float*)d_in[3];
    const float* bg2 = (const float*)d_in[4];
    const float* Wdr = (const float*)d_in[5];
    const float* bdr = (const float*)d_in[6];
    const float* Wdi = (const float*)d_in[7];
    const float* bdi = (const float*)d_in[8];
    float* out = (float*)d_out;

    // workspace layout (141.0 MB total; R1 empirically proved ws >= 168 MB):
    //   [0, 33.5M)      g1b (k1..k2)  -> summ (k3a..k3c)       alias OK
    //   [33.5M, 34.1M)  B2t (conv..k2)
    //   [34.1M, 67.6M)  xb  (conv..k1) -> omgu (k2..k3c)       alias OK
    //   [67.6M, 73.9M)  Bct (conv..k1)
    //   [73.9M, 141.0M) drvb bf16 (k1..k3c)   [if ws fits, else fp32 in out]
    char* ws = (char*)d_ws;
    unsigned short* g1b  = (unsigned short*)(ws + 0);
    float4*         summ = (float4*)(ws + 0);
    unsigned short* B2t  = (unsigned short*)(ws + 33554432);
    unsigned short* xb   = (unsigned short*)(ws + 34078720);
    unsigned short* omgu = (unsigned short*)(ws + 34078720);
    unsigned short* Bct  = (unsigned short*)(ws + 67633152);
    unsigned short* drvb = (unsigned short*)(ws + 73924608);
    const bool drv_bf16 = ws_size >= (size_t)73924608 + 67108864;

    SC sc;
    {
        const double r[S_]  = {1.0, 0.999, 0.9495, 0.9};
        const double th[S_] = {0.0, 0.01, 0.505, 1.0};
        for (int s = 0; s < S_; ++s) {
            sc.are[s] = (float)(r[s] * cos(th[s]));
            sc.aim[s] = (float)(r[s] * sin(th[s]));
            sc.bsc[s] = (r[s] >= 1.0) ? (float)(1.0/16.0) : (float)(1.0 - r[s]);
        }
    }

    // conversions
    kconv_x<<<(BT_*DIN)/1024, 256, 0, stream>>>(x, xb);
    kconv_w<<<dim3(32,8,S_), 256, 0, stream>>>(Wg1, Bct + 0*D_*DIN, DIN, D_, (size_t)768*DIN);
    kconv_w<<<dim3(32,8,S_), 256, 0, stream>>>(Wdr, Bct + 1*D_*DIN, DIN, D_, (size_t)768*DIN);
    kconv_w<<<dim3(32,8,S_), 256, 0, stream>>>(Wdi, Bct + 2*D_*DIN, DIN, D_, (size_t)768*DIN);
    kconv_w<<<dim3(8,8,S_),  256, 0, stream>>>(Wg2, B2t, D_, D_, (size_t)D_*D_);

    // GEMMs
    if (drv_bf16)
        k1_mfma<true><<<dim3(BT_/128, GN/128), 256, 0, stream>>>(
            xb, Bct, bg1, bdr, bdi, g1b, drvb, out);
    else
        k1_mfma<false><<<dim3(BT_/128, GN/128), 256, 0, stream>>>(
            xb, Bct, bg1, bdr, bdi, g1b, drvb, out);
    k2_mfma<<<dim3(BT_/128, D_/128, S_), 256, 0, stream>>>(g1b, B2t, bg2, omgu);

    // scan
    if (drv_bf16) {
        k3a_chunk<true><<<B_*S_*CHUNKS, 128, 0, stream>>>(omgu, drvb, out, summ, sc);
        k3b_scan       <<<(B_*S_*D_)/256, 256, 0, stream>>>(summ);
        k3c_final<true><<<B_*S_*CHUNKS, 128, 0, stream>>>(omgu, drvb, out, out, summ, sc);
    } else {
        k3a_chunk<false><<<B_*S_*CHUNKS, 128, 0, stream>>>(omgu, drvb, out, summ, sc);
        k3b_scan        <<<(B_*S_*D_)/256, 256, 0, stream>>>(summ);
        k3c_final<false><<<B_*S_*CHUNKS, 128, 0, stream>>>(omgu, drvb, out, out, summ, sc);
    }
}